// Round 4
// baseline (136.372 us; speedup 1.0000x reference)
//
#include <hip/hip_runtime.h>

// ExpertCompoundTracker: MoE load-EMA + pairwise co-activation histogram.
// Inputs: expert_indices [N,K] int32, expert_weights (UNUSED),
//         expert_load_ema [E] f32, expert_pair_coactivation [E,E] f32.
// Outputs concat: new_load_ema [64] then new_coact [4096], f32.
//
// R4: R3 was latency-bound (VGPR=16 -> serialized int4 loads, 1 block/CU).
// Fix: 512x256 grid (2 blocks/CU) + EXPLICIT 4-token load batching so the
// compiler keeps 4 global_load_dwordx4 in flight per thread. Keep the XOR
// bank swizzle and fused last-block-done finalize.

#define N_TOKENS    2097152
#define NUM_EXPERTS 64
#define NCELLS      (NUM_EXPERTS * NUM_EXPERTS)  // 4096
#define NBLOCKS     512
#define NTHREADS    256
#define STRIDE      (NBLOCKS * NTHREADS)         // 131072 threads, 16 tokens each

__device__ __forceinline__ void pair_add(int* s, int a, int b) {
    const int lo = min(a, b), hi = max(a, b);
    // bijective swizzle: bank = (hi%32) ^ (lo&31) -> uniform
    atomicAdd(&s[(lo << 6) + (hi ^ (lo & 31))], 1);
}

__device__ __forceinline__ void token_add(int* s, int4 v) {
    pair_add(s, v.x, v.y);
    pair_add(s, v.x, v.z);
    pair_add(s, v.x, v.w);
    pair_add(s, v.y, v.z);
    pair_add(s, v.y, v.w);
    pair_add(s, v.z, v.w);
}

__global__ __launch_bounds__(NTHREADS) void coact_fused_kernel(
    const int* __restrict__ idx,
    const float* __restrict__ ema_in,
    const float* __restrict__ coact_in,
    int* __restrict__ ws,            // [NCELLS] histogram + [1] done-counter
    float* __restrict__ out)
{
    __shared__ int s_coact[NCELLS];  // 16 KB, swizzled upper-triangle cells
    __shared__ int s_last;
    for (int i = threadIdx.x; i < NCELLS; i += NTHREADS) s_coact[i] = 0;
    __syncthreads();

    const int tid = blockIdx.x * NTHREADS + threadIdx.x;
    const int4* __restrict__ idx4 = (const int4*)idx;

    // 16 tokens/thread in 4 batches of 4. Named locals force 4 concurrent
    // global_load_dwordx4 (R3's VGPR=16 proved the pragma alone didn't).
    #pragma unroll
    for (int g = 0; g < 4; ++g) {
        const int base = g * 4 * STRIDE + tid;
        const int4 v0 = idx4[base];
        const int4 v1 = idx4[base + STRIDE];
        const int4 v2 = idx4[base + 2 * STRIDE];
        const int4 v3 = idx4[base + 3 * STRIDE];
        token_add(s_coact, v0);
        token_add(s_coact, v1);
        token_add(s_coact, v2);
        token_add(s_coact, v3);
    }
    __syncthreads();

    // Flush: unswizzle, skip always-zero lower-triangle cells.
    for (int i = threadIdx.x; i < NCELLS; i += NTHREADS) {
        int v = s_coact[i];
        if (v) {
            const int lo = i >> 6;
            const int hi = (i & 63) ^ (lo & 31);
            atomicAdd(&ws[(lo << 6) + hi], v);
        }
    }

    // Last-block-done: release fence + device-scope counter.
    __threadfence();
    if (threadIdx.x == 0) {
        const int done = atomicAdd(&ws[NCELLS], 1);
        s_last = (done == NBLOCKS - 1) ? 1 : 0;
    }
    __syncthreads();
    if (!s_last) return;

    __threadfence();  // acquire side

    // new_coact: mirror upper-triangle ws (diagonal x2 — reference adds
    // .at[a,b] and .at[b,a]).
    for (int c = threadIdx.x; c < NCELLS; c += NTHREADS) {
        const int i = c >> 6, j = c & 63;
        const int lo = min(i, j), hi = max(i, j);
        int d = ws[(lo << 6) + hi];
        if (i == j) d *= 2;
        out[NUM_EXPERTS + c] = coact_in[c] + (float)d;
    }

    // counts[e] = rowsum(sym delta)/3 exactly (each occurrence of e pairs
    // with the other 3 slots, duplicates included).
    if (threadIdx.x < NUM_EXPERTS) {
        const int t = threadIdx.x;
        int rowsum = 0;
        #pragma unroll
        for (int j = 0; j < NUM_EXPERTS; ++j) {
            const int lo = min(t, j), hi = max(t, j);
            int d = ws[(lo << 6) + hi];
            rowsum += (j == t) ? 2 * d : d;
        }
        const int count = rowsum / 3;
        const float load = (float)count / (float)N_TOKENS;
        out[t] = ema_in[t] * 0.99f + load * 0.01f;
    }
}

extern "C" void kernel_launch(void* const* d_in, const int* in_sizes, int n_in,
                              void* d_out, int out_size, void* d_ws, size_t ws_size,
                              hipStream_t stream)
{
    const int*   idx      = (const int*)d_in[0];
    // d_in[1] = expert_weights: unused by the reference -> never read.
    const float* ema_in   = (const float*)d_in[2];
    const float* coact_in = (const float*)d_in[3];
    float*       out      = (float*)d_out;
    int*         ws       = (int*)d_ws;

    // Zero histogram + done-counter (ws is re-poisoned 0xAA each iteration).
    hipMemsetAsync(ws, 0, (NCELLS + 1) * sizeof(int), stream);

    coact_fused_kernel<<<NBLOCKS, NTHREADS, 0, stream>>>(idx, ema_in, coact_in, ws, out);
}

// Round 5
// 106.865 us; speedup vs baseline: 1.2761x; 1.2761x over previous
//
#include <hip/hip_runtime.h>

// ExpertCompoundTracker: MoE load-EMA + pairwise co-activation histogram.
// Inputs: expert_indices [N,K] int32, expert_weights (UNUSED),
//         expert_load_ema [E] f32, expert_pair_coactivation [E,E] f32.
// Outputs concat: new_load_ema [64] then new_coact [4096], f32.
//
// R5: two kernels again (R3/R4's per-block __threadfence = per-block L2
// wb/inv on non-coherent XCD L2s — 16-35us of pure fence cost; kernel
// boundary gives ordering for free). Accum is load-LATENCY bound, not
// LDS-atomic bound (R1 12-at/tok == R2 6-at/tok proves it), so: 8
// tokens/thread, ALL 8 int4 loads issued before any use, pinned with
// sched_barrier(0) so the compiler can't re-serialize them (R3/R4
// VGPR=16/20 showed it does exactly that left to itself).

#define N_TOKENS    2097152
#define NUM_EXPERTS 64
#define NCELLS      (NUM_EXPERTS * NUM_EXPERTS)  // 4096
#define NBLOCKS     512
#define NTHREADS    512
#define STRIDE      (NBLOCKS * NTHREADS)         // 262144 threads -> 8 tokens each

__device__ __forceinline__ void pair_add(int* s, int a, int b) {
    const int lo = min(a, b), hi = max(a, b);
    // bijective swizzle: bank = (hi%32) ^ (lo&31) -> uniform
    atomicAdd(&s[(lo << 6) + (hi ^ (lo & 31))], 1);
}

__device__ __forceinline__ void token_add(int* s, int4 v) {
    pair_add(s, v.x, v.y);
    pair_add(s, v.x, v.z);
    pair_add(s, v.x, v.w);
    pair_add(s, v.y, v.z);
    pair_add(s, v.y, v.w);
    pair_add(s, v.z, v.w);
}

__global__ __launch_bounds__(NTHREADS) void coact_accum_kernel(
    const int* __restrict__ idx, int* __restrict__ ws)
{
    __shared__ int s_coact[NCELLS];  // 16 KB, swizzled upper-triangle cells
    for (int i = threadIdx.x; i < NCELLS; i += NTHREADS) s_coact[i] = 0;
    __syncthreads();

    const int tid = blockIdx.x * NTHREADS + threadIdx.x;
    const int4* __restrict__ idx4 = (const int4*)idx;

    // Phase 1: issue all 8 independent global_load_dwordx4 (4 KB/wave in flight).
    int4 v[8];
    #pragma unroll
    for (int i = 0; i < 8; ++i) v[i] = idx4[tid + i * STRIDE];

    // Pin: nothing crosses — loads stay issued before the first consumer,
    // so there is ONE vmcnt drain instead of 8 serial ~700-cycle round-trips.
    __builtin_amdgcn_sched_barrier(0);

    // Phase 2: 48 LDS atomics (fire-and-forget, no dependent waits).
    #pragma unroll
    for (int i = 0; i < 8; ++i) token_add(s_coact, v[i]);

    __syncthreads();

    // Flush: unswizzle, skip always-zero lower-triangle cells (~2080/block).
    for (int i = threadIdx.x; i < NCELLS; i += NTHREADS) {
        int c = s_coact[i];
        if (c) {
            const int lo = i >> 6;
            const int hi = (i & 63) ^ (lo & 31);
            atomicAdd(&ws[(lo << 6) + hi], c);
        }
    }
}

__global__ __launch_bounds__(256) void finalize_kernel(
    const int* __restrict__ ws,
    const float* __restrict__ ema_in,
    const float* __restrict__ coact_in,
    float* __restrict__ out)
{
    const int t = threadIdx.x;

    // new_coact: mirror upper-triangle ws (diagonal x2 — reference adds
    // .at[a,b] and .at[b,a]).
    for (int c = t; c < NCELLS; c += 256) {
        const int i = c >> 6, j = c & 63;
        const int lo = min(i, j), hi = max(i, j);
        int d = ws[(lo << 6) + hi];
        if (i == j) d *= 2;
        out[NUM_EXPERTS + c] = coact_in[c] + (float)d;
    }

    // counts[e] = rowsum(sym delta)/3 exactly (each occurrence of e pairs
    // with the other 3 slots, duplicates included). L1-warm after loop above.
    if (t < NUM_EXPERTS) {
        int rowsum = 0;
        #pragma unroll
        for (int j = 0; j < NUM_EXPERTS; ++j) {
            const int lo = min(t, j), hi = max(t, j);
            int d = ws[(lo << 6) + hi];
            rowsum += (j == t) ? 2 * d : d;
        }
        const int count = rowsum / 3;
        const float load = (float)count / (float)N_TOKENS;
        out[t] = ema_in[t] * 0.99f + load * 0.01f;
    }
}

extern "C" void kernel_launch(void* const* d_in, const int* in_sizes, int n_in,
                              void* d_out, int out_size, void* d_ws, size_t ws_size,
                              hipStream_t stream)
{
    const int*   idx      = (const int*)d_in[0];
    // d_in[1] = expert_weights: unused by the reference -> never read.
    const float* ema_in   = (const float*)d_in[2];
    const float* coact_in = (const float*)d_in[3];
    float*       out      = (float*)d_out;
    int*         ws       = (int*)d_ws;

    // Zero the 16 KB histogram (ws is re-poisoned 0xAA each iteration).
    hipMemsetAsync(ws, 0, NCELLS * sizeof(int), stream);

    coact_accum_kernel<<<NBLOCKS, NTHREADS, 0, stream>>>(idx, ws);
    finalize_kernel<<<1, 256, 0, stream>>>(ws, ema_in, coact_in, out);
}